// Round 19
// baseline (265.611 us; speedup 1.0000x reference)
//
#include <hip/hip_runtime.h>
#include <hip/hip_bf16.h>
#include <hip/hip_fp16.h>

#define N_NODESC 50000
#define N_EDGESC 500000
#define E_TOT    (N_EDGESC + N_NODESC)   // 550000, with self loops
#define HID      64
#define HEADS_C  8
#define F1       (HEADS_C * HID)         // 512
#define VOCAB_C  40000
#define N_GR     512
#define SCAN_B   196                     // ceil(50000/256)

typedef __attribute__((ext_vector_type(8))) short bf16x8;
typedef __attribute__((ext_vector_type(4))) float f32x4;
typedef __attribute__((ext_vector_type(8))) _Float16 half8;

__device__ __forceinline__ float lrelu(float x) { return x > 0.f ? x : 0.2f * x; }
__device__ __forceinline__ float bf2f(unsigned short u) {
  return __uint_as_float(((unsigned int)u) << 16);
}
__device__ __forceinline__ unsigned short f2bf(float f) {
  unsigned int u = __float_as_uint(f);
  unsigned int r = (u + 0x7fffu + ((u >> 16) & 1u)) >> 16;
  return (unsigned short)r;
}
__device__ __forceinline__ unsigned short f2h(float f) {
  __half h = __float2half(f);
  union { __half h; unsigned short u; } c; c.h = h; return c.u;
}
__device__ __forceinline__ __half2 as_h2(unsigned int v) {
  union { unsigned int u; __half2 h; } c; c.u = v; return c.h;
}
__device__ __forceinline__ unsigned int h2u(__half2 h) {
  union { __half2 h; unsigned int u; } c; c.h = h; return c.u;
}

// ---- zero scratch -------------------------------------------------------
__global__ void k_zero(int* __restrict__ deg, float* __restrict__ pooled) {
  int i = blockIdx.x * 256 + threadIdx.x;
  if (i < N_NODESC) deg[i] = 0;
  if (i < N_GR * HID) pooled[i] = 0.f;
}

// ---- CSR build: deg + per-edge slot in one pass -------------------------
__global__ void k_deg(const int* __restrict__ ei, int* __restrict__ deg,
                      int* __restrict__ eslot) {
  int e = blockIdx.x * blockDim.x + threadIdx.x;
  if (e >= E_TOT) return;
  int dst = (e < N_EDGESC) ? ei[N_EDGESC + e] : (e - N_EDGESC);
  eslot[e] = atomicAdd(&deg[dst], 1);
}

__global__ __launch_bounds__(256) void k_scan1(const int* __restrict__ deg,
                                               int* __restrict__ rowtmp,
                                               int* __restrict__ partials) {
  __shared__ int sh[256];
  int b = blockIdx.x, t = threadIdx.x, i = b * 256 + t;
  int d = (i < N_NODESC) ? deg[i] : 0;
  sh[t] = d;
  __syncthreads();
  for (int o = 1; o < 256; o <<= 1) {
    int v = (t >= o) ? sh[t - o] : 0;
    __syncthreads();
    sh[t] += v;
    __syncthreads();
  }
  if (i < N_NODESC) rowtmp[i] = sh[t];  // inclusive within block
  if (t == 255) partials[b] = sh[255];  // raw block total
}

__global__ __launch_bounds__(256) void k_scan3(const int* __restrict__ deg,
                                               const int* __restrict__ rowtmp,
                                               const int* __restrict__ partials,
                                               int* __restrict__ rowstart) {
  __shared__ int wsum[4];
  int b = blockIdx.x, t = threadIdx.x;
  int acc = 0;
  for (int i = t; i < b; i += 256) acc += partials[i];
#pragma unroll
  for (int o = 32; o; o >>= 1) acc += __shfl_xor(acc, o);
  if ((t & 63) == 0) wsum[t >> 6] = acc;
  __syncthreads();
  int base = wsum[0] + wsum[1] + wsum[2] + wsum[3];
  int i = b * 256 + t;
  if (i < N_NODESC) rowstart[i] = base + rowtmp[i] - deg[i];  // exclusive
  if (i == N_NODESC - 1) rowstart[N_NODESC] = base + rowtmp[i];
}

__global__ void k_scatter(const int* __restrict__ ei, const int* __restrict__ rowstart,
                          const int* __restrict__ eslot, int* __restrict__ esrc) {
  int e = blockIdx.x * blockDim.x + threadIdx.x;
  if (e >= E_TOT) return;
  int src, dst;
  if (e < N_EDGESC) { src = ei[e]; dst = ei[N_EDGESC + e]; }
  else { src = dst = e - N_EDGESC; }
  esrc[rowstart[dst] + eslot[e]] = src;
}

// ---- prep folds + weight converts + Wp transpose, one kernel ------------
__global__ __launch_bounds__(512) void k_prepwconv(const float* __restrict__ W1,
                                                   const float* __restrict__ as1,
                                                   const float* __restrict__ ad1,
                                                   const float* __restrict__ W2,
                                                   const float* __restrict__ as2,
                                                   const float* __restrict__ ad2,
                                                   const float* __restrict__ Wp,
                                                   float* __restrict__ w2sv,
                                                   float* __restrict__ w2dv,
                                                   unsigned short* __restrict__ waB,
                                                   unsigned short* __restrict__ w1bT,
                                                   unsigned short* __restrict__ w2bT,
                                                   unsigned short* __restrict__ wpT) {
  __shared__ float ws[64][65];
  int b = blockIdx.x, t = threadIdx.x;
  if (b < 64) {
    int g = b * 512 + t;
    int c = g >> 6, k = g & 63;
    w1bT[g] = f2bf(W1[(size_t)k * F1 + c]);
  } else if (b < 128) {
    int idx = (b - 64) * 512 + t;
    int c = idx >> 9, k = idx & 511;
    w2bT[idx] = f2bf(W2[(size_t)k * HID + c]);
  } else if (b == 128) {
    int k = t >> 3, h = t & 7;
    float ss = 0.f, dd = 0.f;
    for (int c = 0; c < 64; ++c) {
      float w = W1[k * F1 + h * 64 + c];
      ss += w * as1[h * 64 + c];
      dd += w * ad1[h * 64 + c];
    }
    waB[h * 64 + k] = f2bf(ss);
    waB[(8 + h) * 64 + k] = f2bf(dd);
    float s2 = 0.f, d2 = 0.f;
    for (int c = 0; c < 64; ++c) {
      float w = W2[t * 64 + c];
      s2 += w * as2[c];
      d2 += w * ad2[c];
    }
    w2sv[t] = s2;
    w2dv[t] = d2;
  } else {
    int v0 = (b - 129) * 64;
#pragma unroll
    for (int rep = 0; rep < 8; ++rep) {
      int idx = rep * 512 + t;
      int k = idx >> 6, v = idx & 63;
      ws[k][v] = Wp[(size_t)k * VOCAB_C + v0 + v];
    }
    __syncthreads();
#pragma unroll
    for (int rep = 0; rep < 8; ++rep) {
      int idx = rep * 512 + t;
      int v = idx >> 6, k = idx & 63;
      wpT[(size_t)(v0 + v) * 64 + k] = f2bf(ws[k][v]);
    }
  }
}

// ---- embed gather -> f16 rows + scores1 via bf16 MFMA -------------------
__global__ __launch_bounds__(256) void k_embed(const int* __restrict__ x,
                                               const float* __restrict__ emb,
                                               const unsigned short* __restrict__ waB,
                                               unsigned short* __restrict__ hf,
                                               float* __restrict__ s1s,
                                               float* __restrict__ s1d) {
  int t = threadIdx.x;
  int w = t >> 6, lane = t & 63;
  int lrow = lane & 15, lq = lane >> 4;
  int n0 = blockIdx.x * 64 + w * 16;
  if (n0 >= N_NODESC) return;
  int node = n0 + lrow;
  const float* er = emb + (size_t)x[node] * 64;
  float4 f0 = *reinterpret_cast<const float4*>(er + lq * 8);
  float4 f1 = *reinterpret_cast<const float4*>(er + lq * 8 + 4);
  float4 f2 = *reinterpret_cast<const float4*>(er + 32 + lq * 8);
  float4 f3 = *reinterpret_cast<const float4*>(er + 32 + lq * 8 + 4);
  bf16x8 a0, a1;
  a0[0] = (short)f2bf(f0.x); a0[1] = (short)f2bf(f0.y);
  a0[2] = (short)f2bf(f0.z); a0[3] = (short)f2bf(f0.w);
  a0[4] = (short)f2bf(f1.x); a0[5] = (short)f2bf(f1.y);
  a0[6] = (short)f2bf(f1.z); a0[7] = (short)f2bf(f1.w);
  a1[0] = (short)f2bf(f2.x); a1[1] = (short)f2bf(f2.y);
  a1[2] = (short)f2bf(f2.z); a1[3] = (short)f2bf(f2.w);
  a1[4] = (short)f2bf(f3.x); a1[5] = (short)f2bf(f3.y);
  a1[6] = (short)f2bf(f3.z); a1[7] = (short)f2bf(f3.w);
  half8 h0, h1;
  h0[0] = (_Float16)f0.x; h0[1] = (_Float16)f0.y;
  h0[2] = (_Float16)f0.z; h0[3] = (_Float16)f0.w;
  h0[4] = (_Float16)f1.x; h0[5] = (_Float16)f1.y;
  h0[6] = (_Float16)f1.z; h0[7] = (_Float16)f1.w;
  h1[0] = (_Float16)f2.x; h1[1] = (_Float16)f2.y;
  h1[2] = (_Float16)f2.z; h1[3] = (_Float16)f2.w;
  h1[4] = (_Float16)f3.x; h1[5] = (_Float16)f3.y;
  h1[6] = (_Float16)f3.z; h1[7] = (_Float16)f3.w;
  *reinterpret_cast<half8*>(&hf[(size_t)node * 64 + lq * 8]) = h0;
  *reinterpret_cast<half8*>(&hf[(size_t)node * 64 + 32 + lq * 8]) = h1;
  const bf16x8* brow = reinterpret_cast<const bf16x8*>(waB + lrow * 64 + lq * 8);
  f32x4 acc = {};
  acc = __builtin_amdgcn_mfma_f32_16x16x32_bf16(a0, brow[0], acc, 0, 0, 0);
  acc = __builtin_amdgcn_mfma_f32_16x16x32_bf16(a1, brow[4], acc, 0, 0, 0);
  float* dst = (lrow < 8) ? s1s : s1d;
  int h = lrow & 7;
#pragma unroll
  for (int r = 0; r < 4; ++r)
    dst[(size_t)(n0 + lq * 4 + r) * 8 + h] = acc[r];
}

// ---- layer-1 aggregate: batched gather (16 loads in flight) -------------
__global__ __launch_bounds__(256) void k_agg1(const int* __restrict__ rowstart,
                                              const int* __restrict__ esrc,
                                              const unsigned short* __restrict__ hf,
                                              const float* __restrict__ s1s,
                                              const float* __restrict__ s1d,
                                              unsigned short* __restrict__ agg8) {
  int n = blockIdx.x * 4 + (threadIdx.x >> 6);
  int L = threadIdx.x & 63;
  int eh = L >> 3;  // edge slot (p-phase)
  int hh = L & 7;   // head (p-phase)
  int myh = L >> 3; // head of this lane's output slice
  const int fc = (L & 7) * 8;  // feature chunk in 64-dim embedding
  int r0 = rowstart[n], dg = rowstart[n + 1] - r0;
  float sdst = s1d[n * 8 + hh];
  __half2 ac0 = __float2half2_rn(0.f), ac1 = ac0, ac2 = ac0, ac3 = ac0;
  float dsum = 0.f;
  for (int base = 0; base < dg; base += 16) {
    int i0 = base + eh, i1 = base + 8 + eh;
    float p0 = 0.f, p1 = 0.f;
    int s0 = 0, s1 = 0;
    if (i0 < dg) { s0 = esrc[r0 + i0]; p0 = __expf(lrelu(s1s[s0 * 8 + hh] + sdst)); }
    if (i1 < dg) { s1 = esrc[r0 + i1]; p1 = __expf(lrelu(s1s[s1 * 8 + hh] + sdst)); }
    dsum += p0 + p1;
    int cnt = min(16, dg - base);
    if (cnt == 16) {
      int sjs[16];
#pragma unroll
      for (int j = 0; j < 8; ++j) {
        sjs[j] = __shfl(s0, j << 3);
        sjs[8 + j] = __shfl(s1, j << 3);
      }
      uint4 us[16];
#pragma unroll
      for (int j = 0; j < 16; ++j)
        us[j] = *reinterpret_cast<const uint4*>(&hf[(size_t)sjs[j] * 64 + fc]);
#pragma unroll
      for (int j = 0; j < 8; ++j) {
        __half2 p2 = __float2half2_rn(__shfl(p0, (j << 3) | myh));
        ac0 = __hfma2(as_h2(us[j].x), p2, ac0);
        ac1 = __hfma2(as_h2(us[j].y), p2, ac1);
        ac2 = __hfma2(as_h2(us[j].z), p2, ac2);
        ac3 = __hfma2(as_h2(us[j].w), p2, ac3);
      }
#pragma unroll
      for (int j = 0; j < 8; ++j) {
        __half2 p2 = __float2half2_rn(__shfl(p1, (j << 3) | myh));
        ac0 = __hfma2(as_h2(us[8 + j].x), p2, ac0);
        ac1 = __hfma2(as_h2(us[8 + j].y), p2, ac1);
        ac2 = __hfma2(as_h2(us[8 + j].z), p2, ac2);
        ac3 = __hfma2(as_h2(us[8 + j].w), p2, ac3);
      }
    } else {
      int c0 = min(8, cnt);
      for (int j = 0; j < c0; ++j) {
        float pj = __shfl(p0, (j << 3) | myh);
        int sj = __shfl(s0, j << 3);
        uint4 u = *reinterpret_cast<const uint4*>(&hf[(size_t)sj * 64 + fc]);
        __half2 p2 = __float2half2_rn(pj);
        ac0 = __hfma2(as_h2(u.x), p2, ac0);
        ac1 = __hfma2(as_h2(u.y), p2, ac1);
        ac2 = __hfma2(as_h2(u.z), p2, ac2);
        ac3 = __hfma2(as_h2(u.w), p2, ac3);
      }
      for (int j = 8; j < cnt; ++j) {
        float pj = __shfl(p1, ((j - 8) << 3) | myh);
        int sj = __shfl(s1, (j - 8) << 3);
        uint4 u = *reinterpret_cast<const uint4*>(&hf[(size_t)sj * 64 + fc]);
        __half2 p2 = __float2half2_rn(pj);
        ac0 = __hfma2(as_h2(u.x), p2, ac0);
        ac1 = __hfma2(as_h2(u.y), p2, ac1);
        ac2 = __hfma2(as_h2(u.z), p2, ac2);
        ac3 = __hfma2(as_h2(u.w), p2, ac3);
      }
    }
  }
  dsum += __shfl_xor(dsum, 8);
  dsum += __shfl_xor(dsum, 16);
  dsum += __shfl_xor(dsum, 32);
  float inv = 1.f / (__shfl(dsum, myh) + 1e-16f);
  float2 v0 = __half22float2(ac0);
  float2 v1 = __half22float2(ac1);
  float2 v2 = __half22float2(ac2);
  float2 v3 = __half22float2(ac3);
  uint4 ov;
  ov.x = (unsigned int)f2bf(v0.x * inv) | ((unsigned int)f2bf(v0.y * inv) << 16);
  ov.y = (unsigned int)f2bf(v1.x * inv) | ((unsigned int)f2bf(v1.y * inv) << 16);
  ov.z = (unsigned int)f2bf(v2.x * inv) | ((unsigned int)f2bf(v2.y * inv) << 16);
  ov.w = (unsigned int)f2bf(v3.x * inv) | ((unsigned int)f2bf(v3.y * inv) << 16);
  *reinterpret_cast<uint4*>(&agg8[(size_t)n * F1 + L * 8]) = ov;
}

// ---- fused: h1 = elu(agg8@W1+b1) in LDS, then hp2 = h1@W2 (+scores2) ----
// EXACT round-17 measured-best version (61.5us).
__global__ __launch_bounds__(256) void k_fused12(const unsigned short* __restrict__ agg8,
                                                 const unsigned short* __restrict__ w1bT,
                                                 const float* __restrict__ b1,
                                                 const unsigned short* __restrict__ w2bT,
                                                 const float* __restrict__ w2sv,
                                                 const float* __restrict__ w2dv,
                                                 unsigned short* __restrict__ hp2h,
                                                 float* __restrict__ s2s,
                                                 float* __restrict__ s2d) {
  __shared__ unsigned short Ts[16][520];
  __shared__ float bs[512], wsv[512], wdv[512];
  __shared__ float sredS[4][16], sredD[4][16];
  int t = threadIdx.x;
  int n0 = blockIdx.x * 16;  // 3125 blocks exact
  bs[t] = b1[t]; bs[t + 256] = b1[t + 256];
  wsv[t] = w2sv[t]; wsv[t + 256] = w2sv[t + 256];
  wdv[t] = w2dv[t]; wdv[t + 256] = w2dv[t + 256];
  int w = t >> 6, lane = t & 63;
  int lrow = lane & 15, lq = lane >> 4;
  const unsigned short* arow = agg8 + (size_t)(n0 + lrow) * F1;
  int h0 = 2 * w;
  bf16x8 a00 = *reinterpret_cast<const bf16x8*>(arow + h0 * 64 + lq * 8);
  bf16x8 a01 = *reinterpret_cast<const bf16x8*>(arow + h0 * 64 + 32 + lq * 8);
  bf16x8 a10 = *reinterpret_cast<const bf16x8*>(arow + (h0 + 1) * 64 + lq * 8);
  bf16x8 a11 = *reinterpret_cast<const bf16x8*>(arow + (h0 + 1) * 64 + 32 + lq * 8);
  int c0 = w * 128;
  f32x4 acc[8] = {};
#pragma unroll
  for (int ct = 0; ct < 8; ++ct) {
    int col = c0 + ct * 16 + lrow;
    const bf16x8* brow = reinterpret_cast<const bf16x8*>(w1bT + (size_t)col * 64 + lq * 8);
    if (ct < 4) {
      acc[ct] = __builtin_amdgcn_mfma_f32_16x16x32_bf16(a00, brow[0], acc[ct], 0, 0, 0);
      acc[ct] = __builtin_amdgcn_mfma_f32_16x16x32_bf16(a01, brow[4], acc[ct], 0, 0, 0);
    } else {
      acc[ct] = __builtin_amdgcn_mfma_f32_16x16x32_bf16(a10, brow[0], acc[ct], 0, 0, 0);
      acc[ct] = __builtin_amdgcn_mfma_f32_16x16x32_bf16(a11, brow[4], acc[ct], 0, 0, 0);
    }
  }
  __syncthreads();
  float ssp[4] = {}, ddp[4] = {};
#pragma unroll
  for (int ct = 0; ct < 8; ++ct) {
    int col = c0 + ct * 16 + lrow;
#pragma unroll
    for (int r = 0; r < 4; ++r) {
      float v = acc[ct][r] + bs[col];
      v = v > 0.f ? v : (__expf(v) - 1.f);
      Ts[lq * 4 + r][col] = f2bf(v);
      ssp[r] += v * wsv[col];
      ddp[r] += v * wdv[col];
    }
  }
#pragma unroll
  for (int r = 0; r < 4; ++r) {
#pragma unroll
    for (int o = 1; o < 16; o <<= 1) {
      ssp[r] += __shfl_xor(ssp[r], o);
      ddp[r] += __shfl_xor(ddp[r], o);
    }
  }
  if (lrow == 0) {
#pragma unroll
    for (int r = 0; r < 4; ++r) { sredS[w][lq * 4 + r] = ssp[r]; sredD[w][lq * 4 + r] = ddp[r]; }
  }
  __syncthreads();
  f32x4 acc2 = {};
#pragma unroll 4
  for (int kq = 0; kq < 16; ++kq) {
    int kbase = kq * 32 + lq * 8;
    bf16x8 a = *reinterpret_cast<const bf16x8*>(&Ts[lrow][kbase]);
    bf16x8 b = *reinterpret_cast<const bf16x8*>(w2bT + (size_t)(w * 16 + lrow) * F1 + kbase);
    acc2 = __builtin_amdgcn_mfma_f32_16x16x32_bf16(a, b, acc2, 0, 0, 0);
  }
  if (t < 16) {
    s2s[n0 + t] = sredS[0][t] + sredS[1][t] + sredS[2][t] + sredS[3][t];
    s2d[n0 + t] = sredD[0][t] + sredD[1][t] + sredD[2][t] + sredD[3][t];
  }
#pragma unroll
  for (int r = 0; r < 4; ++r)
    hp2h[(size_t)(n0 + lq * 4 + r) * HID + w * 16 + lrow] = f2h(acc2[r]);
}

// ---- layer-2 aggregate: batched gather (16 loads in flight) -------------
__global__ __launch_bounds__(256) void k_agg2(const int* __restrict__ rowstart,
                                              const int* __restrict__ esrc,
                                              const unsigned short* __restrict__ hp2h,
                                              const float* __restrict__ s2s,
                                              const float* __restrict__ s2d,
                                              const float* __restrict__ b2,
                                              const int* __restrict__ batch,
                                              float* __restrict__ pooled) {
  int n = blockIdx.x * 4 + (threadIdx.x >> 6);
  int lane = threadIdx.x & 63;
  int half = lane >> 5;
  int fl = lane & 31;
  int r0 = rowstart[n], dg = rowstart[n + 1] - r0;
  float sdst = s2d[n];
  __half2 ac = __float2half2_rn(0.f);
  float dsum = 0.f;
  for (int base = 0; base < dg; base += 32) {
    int i = base + fl;
    float p = 0.f;
    int s = 0;
    if (i < dg) {
      s = esrc[r0 + i];
      p = __expf(lrelu(s2s[s] + sdst));
    }
    dsum += p;
    int cnt = min(32, dg - base);
    if (cnt == 32) {
      int sjs[16];
#pragma unroll
      for (int jj = 0; jj < 16; ++jj) sjs[jj] = __shfl(s, 2 * jj + half, 32);
      unsigned int us[16];
#pragma unroll
      for (int jj = 0; jj < 16; ++jj)
        us[jj] = *reinterpret_cast<const unsigned int*>(&hp2h[(size_t)sjs[jj] * 64 + fl * 2]);
#pragma unroll
      for (int jj = 0; jj < 16; ++jj) {
        float pj = __shfl(p, 2 * jj + half, 32);
        ac = __hfma2(as_h2(us[jj]), __float2half2_rn(pj), ac);
      }
    } else {
      for (int j = 0; j < cnt; j += 2) {
        int jj = j + half;
        float pj = __shfl(p, jj, 32);
        int sj = __shfl(s, jj, 32);
        unsigned int hv = *reinterpret_cast<const unsigned int*>(&hp2h[(size_t)sj * 64 + fl * 2]);
        ac = __hfma2(as_h2(hv), __float2half2_rn(pj), ac);
      }
    }
  }
#pragma unroll
  for (int o = 1; o < 32; o <<= 1) dsum += __shfl_xor(dsum, o);
  float inv = 1.f / (dsum + 1e-16f);
  unsigned int other = __shfl_xor(h2u(ac), 32);
  ac = __hadd2(ac, as_h2(other));
  float2 fv = __half22float2(ac);
  int f = 2 * fl + half;
  float o = (half ? fv.y : fv.x) * inv + b2[f];
  atomicAdd(&pooled[batch[n] * 64 + f], o);
}

// ---- final via MFMA: out[512,40000] = pooled @ Wp + bp ------------------
__global__ __launch_bounds__(256) void k_final(const float* __restrict__ pooled,
                                               const unsigned short* __restrict__ wpT,
                                               const float* __restrict__ bp,
                                               float* __restrict__ out) {
  __shared__ unsigned short As[16][72];
  __shared__ float Cs[16][324];
  int t = threadIdx.x;
  int g0 = blockIdx.y * 16;
  int vb = blockIdx.x * 320;
  {
    int g = t >> 4, k4 = (t & 15) * 4;
    float4 pv = *reinterpret_cast<const float4*>(&pooled[(size_t)(g0 + g) * 64 + k4]);
    ushort4 u;
    u.x = f2bf(pv.x); u.y = f2bf(pv.y); u.z = f2bf(pv.z); u.w = f2bf(pv.w);
    *reinterpret_cast<ushort4*>(&As[g][k4]) = u;
  }
  __syncthreads();
  int w = t >> 6, lane = t & 63;
  int lrow = lane & 15, lq = lane >> 4;
  bf16x8 a0 = *reinterpret_cast<const bf16x8*>(&As[lrow][lq * 8]);
  bf16x8 a1 = *reinterpret_cast<const bf16x8*>(&As[lrow][32 + lq * 8]);
#pragma unroll
  for (int ct = 0; ct < 5; ++ct) {
    int cloc = (w * 5 + ct) * 16 + lrow;
    const bf16x8* brow = reinterpret_cast<const bf16x8*>(wpT + (size_t)(vb + cloc) * 64 + lq * 8);
    f32x4 acc = {};
    acc = __builtin_amdgcn_mfma_f32_16x16x32_bf16(a0, brow[0], acc, 0, 0, 0);
    acc = __builtin_amdgcn_mfma_f32_16x16x32_bf16(a1, brow[4], acc, 0, 0, 0);
#pragma unroll
    for (int r = 0; r < 4; ++r) Cs[lq * 4 + r][cloc] = acc[r];
  }
  __syncthreads();
  for (int i = t; i < 1280; i += 256) {
    int r = i / 80, c = i % 80;
    float4 cv = *reinterpret_cast<const float4*>(&Cs[r][c * 4]);
    float4 bv = *reinterpret_cast<const float4*>(&bp[vb + c * 4]);
    cv.x += bv.x; cv.y += bv.y; cv.z += bv.z; cv.w += bv.w;
    *reinterpret_cast<float4*>(&out[(size_t)(g0 + r) * VOCAB_C + vb + c * 4]) = cv;
  }
}

extern "C" void kernel_launch(void* const* d_in, const int* in_sizes, int n_in,
                              void* d_out, int out_size, void* d_ws, size_t ws_size,
                              hipStream_t stream) {
  const int*   x     = (const int*)d_in[0];
  const int*   ei    = (const int*)d_in[1];
  const int*   batch = (const int*)d_in[2];
  const float* emb   = (const float*)d_in[3];
  const float* W1    = (const float*)d_in[4];
  const float* as1   = (const float*)d_in[5];
  const float* ad1   = (const float*)d_in[6];
  const float* b1    = (const float*)d_in[7];
  const float* W2    = (const float*)d_in[8];
  const float* as2   = (const float*)d_in[9];
  const float* ad2   = (const float*)d_in[10];
  const float* b2    = (const float*)d_in[11];
  const float* Wp    = (const float*)d_in[12];
  const float* bp    = (const float*)d_in[13];
  float* out = (float*)d_out;

  char* ws = (char*)d_ws;
  size_t off = 0;
#define WS_ALLOC(T, name, bytes) T name = (T)(ws + off); off += (((size_t)(bytes)) + 255) & ~(size_t)255;
  WS_ALLOC(unsigned short*, hf,   (size_t)N_NODESC * HID * 2)
  WS_ALLOC(unsigned short*, agg8, (size_t)N_NODESC * F1 * 2)
  WS_ALLOC(unsigned short*, hp2h, (size_t)N_NODESC * HID * 2)
  WS_ALLOC(unsigned short*, w1bT, 512 * 64 * 2)
  WS_ALLOC(unsigned short*, w2bT, 64 * 512 * 2)
  WS_ALLOC(unsigned short*, wpT,  (size_t)VOCAB_C * HID * 2)
  WS_ALLOC(unsigned short*, waB,  16 * 64 * 2)
  WS_ALLOC(float*, s1s,  (size_t)N_NODESC * HEADS_C * 4)
  WS_ALLOC(float*, s1d,  (size_t)N_NODESC * HEADS_C * 4)
  WS_ALLOC(float*, s2s,  (size_t)N_NODESC * 4)
  WS_ALLOC(float*, s2d,  (size_t)N_NODESC * 4)
  WS_ALLOC(float*, pooled, (size_t)N_GR * HID * 4)
  WS_ALLOC(float*, w2sv, 512 * 4)
  WS_ALLOC(float*, w2dv, 512 * 4)
  WS_ALLOC(int*,   deg,      (size_t)N_NODESC * 4)
  WS_ALLOC(int*,   rowstart, (size_t)(N_NODESC + 1) * 4)
  WS_ALLOC(int*,   rowtmp,   (size_t)N_NODESC * 4)
  WS_ALLOC(int*,   partials, 256 * 4)
  WS_ALLOC(int*,   eslot,    (size_t)E_TOT * 4)
  WS_ALLOC(int*,   esrc,     (size_t)E_TOT * 4)
#undef WS_ALLOC
  (void)ws_size; (void)in_sizes; (void)n_in; (void)out_size;

  int ethreads = 256, eblocks = (E_TOT + 255) / 256;
  k_zero<<<SCAN_B, 256, 0, stream>>>(deg, pooled);
  k_deg<<<eblocks, ethreads, 0, stream>>>(ei, deg, eslot);
  k_scan1<<<SCAN_B, 256, 0, stream>>>(deg, rowtmp, partials);
  k_scan3<<<SCAN_B, 256, 0, stream>>>(deg, rowtmp, partials, rowstart);
  k_scatter<<<eblocks, ethreads, 0, stream>>>(ei, rowstart, eslot, esrc);
  k_prepwconv<<<129 + VOCAB_C / 64, 512, 0, stream>>>(
      W1, as1, ad1, W2, as2, ad2, Wp,
      w2sv, w2dv, waB, w1bT, w2bT, wpT);

  k_embed<<<(N_NODESC + 63) / 64, 256, 0, stream>>>(x, emb, waB, hf, s1s, s1d);
  k_agg1<<<N_NODESC / 4, 256, 0, stream>>>(rowstart, esrc, hf, s1s, s1d, agg8);
  k_fused12<<<N_NODESC / 16, 256, 0, stream>>>(agg8, w1bT, b1, w2bT, w2sv, w2dv,
                                               hp2h, s2s, s2d);
  k_agg2<<<N_NODESC / 4, 256, 0, stream>>>(rowstart, esrc, hp2h, s2s, s2d, b2, batch, pooled);

  k_final<<<dim3(VOCAB_C / 320, N_GR / 16), 256, 0, stream>>>(pooled, wpT, bp, out);
}

// Round 20
// 234.592 us; speedup vs baseline: 1.1322x; 1.1322x over previous
//
#include <hip/hip_runtime.h>
#include <hip/hip_bf16.h>
#include <hip/hip_fp16.h>

#define N_NODESC 50000
#define N_EDGESC 500000
#define E_TOT    (N_EDGESC + N_NODESC)   // 550000, with self loops
#define HID      64
#define HEADS_C  8
#define F1       (HEADS_C * HID)         // 512
#define VOCAB_C  40000
#define N_GR     512
#define SCAN_B   196                     // ceil(50000/256)

typedef __attribute__((ext_vector_type(8))) short bf16x8;
typedef __attribute__((ext_vector_type(4))) float f32x4;
typedef __attribute__((ext_vector_type(8))) _Float16 half8;

__device__ __forceinline__ float lrelu(float x) { return x > 0.f ? x : 0.2f * x; }
__device__ __forceinline__ float bf2f(unsigned short u) {
  return __uint_as_float(((unsigned int)u) << 16);
}
__device__ __forceinline__ unsigned short f2bf(float f) {
  unsigned int u = __float_as_uint(f);
  unsigned int r = (u + 0x7fffu + ((u >> 16) & 1u)) >> 16;
  return (unsigned short)r;
}
__device__ __forceinline__ unsigned short f2h(float f) {
  __half h = __float2half(f);
  union { __half h; unsigned short u; } c; c.h = h; return c.u;
}
__device__ __forceinline__ __half2 as_h2(unsigned int v) {
  union { unsigned int u; __half2 h; } c; c.u = v; return c.h;
}
__device__ __forceinline__ unsigned int h2u(__half2 h) {
  union { __half2 h; unsigned int u; } c; c.h = h; return c.u;
}

// ---- zero scratch -------------------------------------------------------
__global__ void k_zero(int* __restrict__ deg, float* __restrict__ pooled) {
  int i = blockIdx.x * 256 + threadIdx.x;
  if (i < N_NODESC) deg[i] = 0;
  if (i < N_GR * HID) pooled[i] = 0.f;
}

// ---- CSR build: deg + per-edge slot in one pass -------------------------
__global__ void k_deg(const int* __restrict__ ei, int* __restrict__ deg,
                      int* __restrict__ eslot) {
  int e = blockIdx.x * blockDim.x + threadIdx.x;
  if (e >= E_TOT) return;
  int dst = (e < N_EDGESC) ? ei[N_EDGESC + e] : (e - N_EDGESC);
  eslot[e] = atomicAdd(&deg[dst], 1);
}

__global__ __launch_bounds__(256) void k_scan1(const int* __restrict__ deg,
                                               int* __restrict__ rowtmp,
                                               int* __restrict__ partials) {
  __shared__ int sh[256];
  int b = blockIdx.x, t = threadIdx.x, i = b * 256 + t;
  int d = (i < N_NODESC) ? deg[i] : 0;
  sh[t] = d;
  __syncthreads();
  for (int o = 1; o < 256; o <<= 1) {
    int v = (t >= o) ? sh[t - o] : 0;
    __syncthreads();
    sh[t] += v;
    __syncthreads();
  }
  if (i < N_NODESC) rowtmp[i] = sh[t];  // inclusive within block
  if (t == 255) partials[b] = sh[255];  // raw block total
}

__global__ __launch_bounds__(256) void k_scan3(const int* __restrict__ deg,
                                               const int* __restrict__ rowtmp,
                                               const int* __restrict__ partials,
                                               int* __restrict__ rowstart) {
  __shared__ int wsum[4];
  int b = blockIdx.x, t = threadIdx.x;
  int acc = 0;
  for (int i = t; i < b; i += 256) acc += partials[i];
#pragma unroll
  for (int o = 32; o; o >>= 1) acc += __shfl_xor(acc, o);
  if ((t & 63) == 0) wsum[t >> 6] = acc;
  __syncthreads();
  int base = wsum[0] + wsum[1] + wsum[2] + wsum[3];
  int i = b * 256 + t;
  if (i < N_NODESC) rowstart[i] = base + rowtmp[i] - deg[i];  // exclusive
  if (i == N_NODESC - 1) rowstart[N_NODESC] = base + rowtmp[i];
}

__global__ void k_scatter(const int* __restrict__ ei, const int* __restrict__ rowstart,
                          const int* __restrict__ eslot, int* __restrict__ esrc) {
  int e = blockIdx.x * blockDim.x + threadIdx.x;
  if (e >= E_TOT) return;
  int src, dst;
  if (e < N_EDGESC) { src = ei[e]; dst = ei[N_EDGESC + e]; }
  else { src = dst = e - N_EDGESC; }
  esrc[rowstart[dst] + eslot[e]] = src;
}

// ---- prep folds + weight converts + Wp transpose, one kernel ------------
__global__ __launch_bounds__(512) void k_prepwconv(const float* __restrict__ W1,
                                                   const float* __restrict__ as1,
                                                   const float* __restrict__ ad1,
                                                   const float* __restrict__ W2,
                                                   const float* __restrict__ as2,
                                                   const float* __restrict__ ad2,
                                                   const float* __restrict__ Wp,
                                                   float* __restrict__ w2sv,
                                                   float* __restrict__ w2dv,
                                                   unsigned short* __restrict__ waB,
                                                   unsigned short* __restrict__ w1bT,
                                                   unsigned short* __restrict__ w2bT,
                                                   unsigned short* __restrict__ wpT) {
  __shared__ float ws[64][65];
  int b = blockIdx.x, t = threadIdx.x;
  if (b < 64) {
    int g = b * 512 + t;
    int c = g >> 6, k = g & 63;
    w1bT[g] = f2bf(W1[(size_t)k * F1 + c]);
  } else if (b < 128) {
    int idx = (b - 64) * 512 + t;
    int c = idx >> 9, k = idx & 511;
    w2bT[idx] = f2bf(W2[(size_t)k * HID + c]);
  } else if (b == 128) {
    int k = t >> 3, h = t & 7;
    float ss = 0.f, dd = 0.f;
    for (int c = 0; c < 64; ++c) {
      float w = W1[k * F1 + h * 64 + c];
      ss += w * as1[h * 64 + c];
      dd += w * ad1[h * 64 + c];
    }
    waB[h * 64 + k] = f2bf(ss);
    waB[(8 + h) * 64 + k] = f2bf(dd);
    float s2 = 0.f, d2 = 0.f;
    for (int c = 0; c < 64; ++c) {
      float w = W2[t * 64 + c];
      s2 += w * as2[c];
      d2 += w * ad2[c];
    }
    w2sv[t] = s2;
    w2dv[t] = d2;
  } else {
    int v0 = (b - 129) * 64;
#pragma unroll
    for (int rep = 0; rep < 8; ++rep) {
      int idx = rep * 512 + t;
      int k = idx >> 6, v = idx & 63;
      ws[k][v] = Wp[(size_t)k * VOCAB_C + v0 + v];
    }
    __syncthreads();
#pragma unroll
    for (int rep = 0; rep < 8; ++rep) {
      int idx = rep * 512 + t;
      int v = idx >> 6, k = idx & 63;
      wpT[(size_t)(v0 + v) * 64 + k] = f2bf(ws[k][v]);
    }
  }
}

// ---- embed gather -> f16 rows + scores1 via bf16 MFMA -------------------
__global__ __launch_bounds__(256) void k_embed(const int* __restrict__ x,
                                               const float* __restrict__ emb,
                                               const unsigned short* __restrict__ waB,
                                               unsigned short* __restrict__ hf,
                                               float* __restrict__ s1s,
                                               float* __restrict__ s1d) {
  int t = threadIdx.x;
  int w = t >> 6, lane = t & 63;
  int lrow = lane & 15, lq = lane >> 4;
  int n0 = blockIdx.x * 64 + w * 16;
  if (n0 >= N_NODESC) return;
  int node = n0 + lrow;
  const float* er = emb + (size_t)x[node] * 64;
  float4 f0 = *reinterpret_cast<const float4*>(er + lq * 8);
  float4 f1 = *reinterpret_cast<const float4*>(er + lq * 8 + 4);
  float4 f2 = *reinterpret_cast<const float4*>(er + 32 + lq * 8);
  float4 f3 = *reinterpret_cast<const float4*>(er + 32 + lq * 8 + 4);
  bf16x8 a0, a1;
  a0[0] = (short)f2bf(f0.x); a0[1] = (short)f2bf(f0.y);
  a0[2] = (short)f2bf(f0.z); a0[3] = (short)f2bf(f0.w);
  a0[4] = (short)f2bf(f1.x); a0[5] = (short)f2bf(f1.y);
  a0[6] = (short)f2bf(f1.z); a0[7] = (short)f2bf(f1.w);
  a1[0] = (short)f2bf(f2.x); a1[1] = (short)f2bf(f2.y);
  a1[2] = (short)f2bf(f2.z); a1[3] = (short)f2bf(f2.w);
  a1[4] = (short)f2bf(f3.x); a1[5] = (short)f2bf(f3.y);
  a1[6] = (short)f2bf(f3.z); a1[7] = (short)f2bf(f3.w);
  half8 h0, h1;
  h0[0] = (_Float16)f0.x; h0[1] = (_Float16)f0.y;
  h0[2] = (_Float16)f0.z; h0[3] = (_Float16)f0.w;
  h0[4] = (_Float16)f1.x; h0[5] = (_Float16)f1.y;
  h0[6] = (_Float16)f1.z; h0[7] = (_Float16)f1.w;
  h1[0] = (_Float16)f2.x; h1[1] = (_Float16)f2.y;
  h1[2] = (_Float16)f2.z; h1[3] = (_Float16)f2.w;
  h1[4] = (_Float16)f3.x; h1[5] = (_Float16)f3.y;
  h1[6] = (_Float16)f3.z; h1[7] = (_Float16)f3.w;
  *reinterpret_cast<half8*>(&hf[(size_t)node * 64 + lq * 8]) = h0;
  *reinterpret_cast<half8*>(&hf[(size_t)node * 64 + 32 + lq * 8]) = h1;
  const bf16x8* brow = reinterpret_cast<const bf16x8*>(waB + lrow * 64 + lq * 8);
  f32x4 acc = {};
  acc = __builtin_amdgcn_mfma_f32_16x16x32_bf16(a0, brow[0], acc, 0, 0, 0);
  acc = __builtin_amdgcn_mfma_f32_16x16x32_bf16(a1, brow[4], acc, 0, 0, 0);
  float* dst = (lrow < 8) ? s1s : s1d;
  int h = lrow & 7;
#pragma unroll
  for (int r = 0; r < 4; ++r)
    dst[(size_t)(n0 + lq * 4 + r) * 8 + h] = acc[r];
}

// ---- layer-1 aggregate: batched gather (8 loads in flight) --------------
// EXACT measured-best version (234.7us total config).
__global__ __launch_bounds__(256) void k_agg1(const int* __restrict__ rowstart,
                                              const int* __restrict__ esrc,
                                              const unsigned short* __restrict__ hf,
                                              const float* __restrict__ s1s,
                                              const float* __restrict__ s1d,
                                              unsigned short* __restrict__ agg8) {
  int n = blockIdx.x * 4 + (threadIdx.x >> 6);
  int L = threadIdx.x & 63;
  int eh = L >> 3;  // edge slot (p-phase)
  int hh = L & 7;   // head (p-phase)
  int myh = L >> 3; // head of this lane's output slice
  const int fc = (L & 7) * 8;  // feature chunk in 64-dim embedding
  int r0 = rowstart[n], dg = rowstart[n + 1] - r0;
  float sdst = s1d[n * 8 + hh];
  __half2 ac0 = __float2half2_rn(0.f), ac1 = ac0, ac2 = ac0, ac3 = ac0;
  float dsum = 0.f;
  for (int base = 0; base < dg; base += 8) {
    int i = base + eh;
    float p = 0.f;
    int s = 0;
    if (i < dg) {
      s = esrc[r0 + i];
      p = __expf(lrelu(s1s[s * 8 + hh] + sdst));
    }
    dsum += p;
    int cnt = min(8, dg - base);
    if (cnt == 8) {
      int sjs[8];
#pragma unroll
      for (int j = 0; j < 8; ++j) sjs[j] = __shfl(s, j << 3);
      uint4 us[8];
#pragma unroll
      for (int j = 0; j < 8; ++j)
        us[j] = *reinterpret_cast<const uint4*>(&hf[(size_t)sjs[j] * 64 + fc]);
#pragma unroll
      for (int j = 0; j < 8; ++j) {
        __half2 p2 = __float2half2_rn(__shfl(p, (j << 3) | myh));
        ac0 = __hfma2(as_h2(us[j].x), p2, ac0);
        ac1 = __hfma2(as_h2(us[j].y), p2, ac1);
        ac2 = __hfma2(as_h2(us[j].z), p2, ac2);
        ac3 = __hfma2(as_h2(us[j].w), p2, ac3);
      }
    } else {
      for (int j = 0; j < cnt; ++j) {
        float pj = __shfl(p, (j << 3) | myh);
        int sj = __shfl(s, j << 3);
        uint4 u = *reinterpret_cast<const uint4*>(&hf[(size_t)sj * 64 + fc]);
        __half2 p2 = __float2half2_rn(pj);
        ac0 = __hfma2(as_h2(u.x), p2, ac0);
        ac1 = __hfma2(as_h2(u.y), p2, ac1);
        ac2 = __hfma2(as_h2(u.z), p2, ac2);
        ac3 = __hfma2(as_h2(u.w), p2, ac3);
      }
    }
  }
  dsum += __shfl_xor(dsum, 8);
  dsum += __shfl_xor(dsum, 16);
  dsum += __shfl_xor(dsum, 32);
  float inv = 1.f / (__shfl(dsum, myh) + 1e-16f);
  float2 v0 = __half22float2(ac0);
  float2 v1 = __half22float2(ac1);
  float2 v2 = __half22float2(ac2);
  float2 v3 = __half22float2(ac3);
  uint4 ov;
  ov.x = (unsigned int)f2bf(v0.x * inv) | ((unsigned int)f2bf(v0.y * inv) << 16);
  ov.y = (unsigned int)f2bf(v1.x * inv) | ((unsigned int)f2bf(v1.y * inv) << 16);
  ov.z = (unsigned int)f2bf(v2.x * inv) | ((unsigned int)f2bf(v2.y * inv) << 16);
  ov.w = (unsigned int)f2bf(v3.x * inv) | ((unsigned int)f2bf(v3.y * inv) << 16);
  *reinterpret_cast<uint4*>(&agg8[(size_t)n * F1 + L * 8]) = ov;
}

// ---- fused: h1 = elu(agg8@W1+b1) in LDS, then hp2 = h1@W2 (+scores2) ----
// EXACT measured-best version (61.5us).
__global__ __launch_bounds__(256) void k_fused12(const unsigned short* __restrict__ agg8,
                                                 const unsigned short* __restrict__ w1bT,
                                                 const float* __restrict__ b1,
                                                 const unsigned short* __restrict__ w2bT,
                                                 const float* __restrict__ w2sv,
                                                 const float* __restrict__ w2dv,
                                                 unsigned short* __restrict__ hp2h,
                                                 float* __restrict__ s2s,
                                                 float* __restrict__ s2d) {
  __shared__ unsigned short Ts[16][520];
  __shared__ float bs[512], wsv[512], wdv[512];
  __shared__ float sredS[4][16], sredD[4][16];
  int t = threadIdx.x;
  int n0 = blockIdx.x * 16;  // 3125 blocks exact
  bs[t] = b1[t]; bs[t + 256] = b1[t + 256];
  wsv[t] = w2sv[t]; wsv[t + 256] = w2sv[t + 256];
  wdv[t] = w2dv[t]; wdv[t + 256] = w2dv[t + 256];
  int w = t >> 6, lane = t & 63;
  int lrow = lane & 15, lq = lane >> 4;
  const unsigned short* arow = agg8 + (size_t)(n0 + lrow) * F1;
  int h0 = 2 * w;
  bf16x8 a00 = *reinterpret_cast<const bf16x8*>(arow + h0 * 64 + lq * 8);
  bf16x8 a01 = *reinterpret_cast<const bf16x8*>(arow + h0 * 64 + 32 + lq * 8);
  bf16x8 a10 = *reinterpret_cast<const bf16x8*>(arow + (h0 + 1) * 64 + lq * 8);
  bf16x8 a11 = *reinterpret_cast<const bf16x8*>(arow + (h0 + 1) * 64 + 32 + lq * 8);
  int c0 = w * 128;
  f32x4 acc[8] = {};
#pragma unroll
  for (int ct = 0; ct < 8; ++ct) {
    int col = c0 + ct * 16 + lrow;
    const bf16x8* brow = reinterpret_cast<const bf16x8*>(w1bT + (size_t)col * 64 + lq * 8);
    if (ct < 4) {
      acc[ct] = __builtin_amdgcn_mfma_f32_16x16x32_bf16(a00, brow[0], acc[ct], 0, 0, 0);
      acc[ct] = __builtin_amdgcn_mfma_f32_16x16x32_bf16(a01, brow[4], acc[ct], 0, 0, 0);
    } else {
      acc[ct] = __builtin_amdgcn_mfma_f32_16x16x32_bf16(a10, brow[0], acc[ct], 0, 0, 0);
      acc[ct] = __builtin_amdgcn_mfma_f32_16x16x32_bf16(a11, brow[4], acc[ct], 0, 0, 0);
    }
  }
  __syncthreads();
  float ssp[4] = {}, ddp[4] = {};
#pragma unroll
  for (int ct = 0; ct < 8; ++ct) {
    int col = c0 + ct * 16 + lrow;
#pragma unroll
    for (int r = 0; r < 4; ++r) {
      float v = acc[ct][r] + bs[col];
      v = v > 0.f ? v : (__expf(v) - 1.f);
      Ts[lq * 4 + r][col] = f2bf(v);
      ssp[r] += v * wsv[col];
      ddp[r] += v * wdv[col];
    }
  }
#pragma unroll
  for (int r = 0; r < 4; ++r) {
#pragma unroll
    for (int o = 1; o < 16; o <<= 1) {
      ssp[r] += __shfl_xor(ssp[r], o);
      ddp[r] += __shfl_xor(ddp[r], o);
    }
  }
  if (lrow == 0) {
#pragma unroll
    for (int r = 0; r < 4; ++r) { sredS[w][lq * 4 + r] = ssp[r]; sredD[w][lq * 4 + r] = ddp[r]; }
  }
  __syncthreads();
  f32x4 acc2 = {};
#pragma unroll 4
  for (int kq = 0; kq < 16; ++kq) {
    int kbase = kq * 32 + lq * 8;
    bf16x8 a = *reinterpret_cast<const bf16x8*>(&Ts[lrow][kbase]);
    bf16x8 b = *reinterpret_cast<const bf16x8*>(w2bT + (size_t)(w * 16 + lrow) * F1 + kbase);
    acc2 = __builtin_amdgcn_mfma_f32_16x16x32_bf16(a, b, acc2, 0, 0, 0);
  }
  if (t < 16) {
    s2s[n0 + t] = sredS[0][t] + sredS[1][t] + sredS[2][t] + sredS[3][t];
    s2d[n0 + t] = sredD[0][t] + sredD[1][t] + sredD[2][t] + sredD[3][t];
  }
#pragma unroll
  for (int r = 0; r < 4; ++r)
    hp2h[(size_t)(n0 + lq * 4 + r) * HID + w * 16 + lrow] = f2h(acc2[r]);
}

// ---- layer-2 aggregate: batched gather (16 loads in flight) -------------
__global__ __launch_bounds__(256) void k_agg2(const int* __restrict__ rowstart,
                                              const int* __restrict__ esrc,
                                              const unsigned short* __restrict__ hp2h,
                                              const float* __restrict__ s2s,
                                              const float* __restrict__ s2d,
                                              const float* __restrict__ b2,
                                              const int* __restrict__ batch,
                                              float* __restrict__ pooled) {
  int n = blockIdx.x * 4 + (threadIdx.x >> 6);
  int lane = threadIdx.x & 63;
  int half = lane >> 5;
  int fl = lane & 31;
  int r0 = rowstart[n], dg = rowstart[n + 1] - r0;
  float sdst = s2d[n];
  __half2 ac = __float2half2_rn(0.f);
  float dsum = 0.f;
  for (int base = 0; base < dg; base += 32) {
    int i = base + fl;
    float p = 0.f;
    int s = 0;
    if (i < dg) {
      s = esrc[r0 + i];
      p = __expf(lrelu(s2s[s] + sdst));
    }
    dsum += p;
    int cnt = min(32, dg - base);
    if (cnt == 32) {
      int sjs[16];
#pragma unroll
      for (int jj = 0; jj < 16; ++jj) sjs[jj] = __shfl(s, 2 * jj + half, 32);
      unsigned int us[16];
#pragma unroll
      for (int jj = 0; jj < 16; ++jj)
        us[jj] = *reinterpret_cast<const unsigned int*>(&hp2h[(size_t)sjs[jj] * 64 + fl * 2]);
#pragma unroll
      for (int jj = 0; jj < 16; ++jj) {
        float pj = __shfl(p, 2 * jj + half, 32);
        ac = __hfma2(as_h2(us[jj]), __float2half2_rn(pj), ac);
      }
    } else {
      for (int j = 0; j < cnt; j += 2) {
        int jj = j + half;
        float pj = __shfl(p, jj, 32);
        int sj = __shfl(s, jj, 32);
        unsigned int hv = *reinterpret_cast<const unsigned int*>(&hp2h[(size_t)sj * 64 + fl * 2]);
        ac = __hfma2(as_h2(hv), __float2half2_rn(pj), ac);
      }
    }
  }
#pragma unroll
  for (int o = 1; o < 32; o <<= 1) dsum += __shfl_xor(dsum, o);
  float inv = 1.f / (dsum + 1e-16f);
  unsigned int other = __shfl_xor(h2u(ac), 32);
  ac = __hadd2(ac, as_h2(other));
  float2 fv = __half22float2(ac);
  int f = 2 * fl + half;
  float o = (half ? fv.y : fv.x) * inv + b2[f];
  atomicAdd(&pooled[batch[n] * 64 + f], o);
}

// ---- final via MFMA: out[512,40000] = pooled @ Wp + bp ------------------
__global__ __launch_bounds__(256) void k_final(const float* __restrict__ pooled,
                                               const unsigned short* __restrict__ wpT,
                                               const float* __restrict__ bp,
                                               float* __restrict__ out) {
  __shared__ unsigned short As[16][72];
  __shared__ float Cs[16][324];
  int t = threadIdx.x;
  int g0 = blockIdx.y * 16;
  int vb = blockIdx.x * 320;
  {
    int g = t >> 4, k4 = (t & 15) * 4;
    float4 pv = *reinterpret_cast<const float4*>(&pooled[(size_t)(g0 + g) * 64 + k4]);
    ushort4 u;
    u.x = f2bf(pv.x); u.y = f2bf(pv.y); u.z = f2bf(pv.z); u.w = f2bf(pv.w);
    *reinterpret_cast<ushort4*>(&As[g][k4]) = u;
  }
  __syncthreads();
  int w = t >> 6, lane = t & 63;
  int lrow = lane & 15, lq = lane >> 4;
  bf16x8 a0 = *reinterpret_cast<const bf16x8*>(&As[lrow][lq * 8]);
  bf16x8 a1 = *reinterpret_cast<const bf16x8*>(&As[lrow][32 + lq * 8]);
#pragma unroll
  for (int ct = 0; ct < 5; ++ct) {
    int cloc = (w * 5 + ct) * 16 + lrow;
    const bf16x8* brow = reinterpret_cast<const bf16x8*>(wpT + (size_t)(vb + cloc) * 64 + lq * 8);
    f32x4 acc = {};
    acc = __builtin_amdgcn_mfma_f32_16x16x32_bf16(a0, brow[0], acc, 0, 0, 0);
    acc = __builtin_amdgcn_mfma_f32_16x16x32_bf16(a1, brow[4], acc, 0, 0, 0);
#pragma unroll
    for (int r = 0; r < 4; ++r) Cs[lq * 4 + r][cloc] = acc[r];
  }
  __syncthreads();
  for (int i = t; i < 1280; i += 256) {
    int r = i / 80, c = i % 80;
    float4 cv = *reinterpret_cast<const float4*>(&Cs[r][c * 4]);
    float4 bv = *reinterpret_cast<const float4*>(&bp[vb + c * 4]);
    cv.x += bv.x; cv.y += bv.y; cv.z += bv.z; cv.w += bv.w;
    *reinterpret_cast<float4*>(&out[(size_t)(g0 + r) * VOCAB_C + vb + c * 4]) = cv;
  }
}

extern "C" void kernel_launch(void* const* d_in, const int* in_sizes, int n_in,
                              void* d_out, int out_size, void* d_ws, size_t ws_size,
                              hipStream_t stream) {
  const int*   x     = (const int*)d_in[0];
  const int*   ei    = (const int*)d_in[1];
  const int*   batch = (const int*)d_in[2];
  const float* emb   = (const float*)d_in[3];
  const float* W1    = (const float*)d_in[4];
  const float* as1   = (const float*)d_in[5];
  const float* ad1   = (const float*)d_in[6];
  const float* b1    = (const float*)d_in[7];
  const float* W2    = (const float*)d_in[8];
  const float* as2   = (const float*)d_in[9];
  const float* ad2   = (const float*)d_in[10];
  const float* b2    = (const float*)d_in[11];
  const float* Wp    = (const float*)d_in[12];
  const float* bp    = (const float*)d_in[13];
  float* out = (float*)d_out;

  char* ws = (char*)d_ws;
  size_t off = 0;
#define WS_ALLOC(T, name, bytes) T name = (T)(ws + off); off += (((size_t)(bytes)) + 255) & ~(size_t)255;
  WS_ALLOC(unsigned short*, hf,   (size_t)N_NODESC * HID * 2)
  WS_ALLOC(unsigned short*, agg8, (size_t)N_NODESC * F1 * 2)
  WS_ALLOC(unsigned short*, hp2h, (size_t)N_NODESC * HID * 2)
  WS_ALLOC(unsigned short*, w1bT, 512 * 64 * 2)
  WS_ALLOC(unsigned short*, w2bT, 64 * 512 * 2)
  WS_ALLOC(unsigned short*, wpT,  (size_t)VOCAB_C * HID * 2)
  WS_ALLOC(unsigned short*, waB,  16 * 64 * 2)
  WS_ALLOC(float*, s1s,  (size_t)N_NODESC * HEADS_C * 4)
  WS_ALLOC(float*, s1d,  (size_t)N_NODESC * HEADS_C * 4)
  WS_ALLOC(float*, s2s,  (size_t)N_NODESC * 4)
  WS_ALLOC(float*, s2d,  (size_t)N_NODESC * 4)
  WS_ALLOC(float*, pooled, (size_t)N_GR * HID * 4)
  WS_ALLOC(float*, w2sv, 512 * 4)
  WS_ALLOC(float*, w2dv, 512 * 4)
  WS_ALLOC(int*,   deg,      (size_t)N_NODESC * 4)
  WS_ALLOC(int*,   rowstart, (size_t)(N_NODESC + 1) * 4)
  WS_ALLOC(int*,   rowtmp,   (size_t)N_NODESC * 4)
  WS_ALLOC(int*,   partials, 256 * 4)
  WS_ALLOC(int*,   eslot,    (size_t)E_TOT * 4)
  WS_ALLOC(int*,   esrc,     (size_t)E_TOT * 4)
#undef WS_ALLOC
  (void)ws_size; (void)in_sizes; (void)n_in; (void)out_size;

  int ethreads = 256, eblocks = (E_TOT + 255) / 256;
  k_zero<<<SCAN_B, 256, 0, stream>>>(deg, pooled);
  k_deg<<<eblocks, ethreads, 0, stream>>>(ei, deg, eslot);
  k_scan1<<<SCAN_B, 256, 0, stream>>>(deg, rowtmp, partials);
  k_scan3<<<SCAN_B, 256, 0, stream>>>(deg, rowtmp, partials, rowstart);
  k_scatter<<<eblocks, ethreads, 0, stream>>>(ei, rowstart, eslot, esrc);
  k_prepwconv<<<129 + VOCAB_C / 64, 512, 0, stream>>>(
      W1, as1, ad1, W2, as2, ad2, Wp,
      w2sv, w2dv, waB, w1bT, w2bT, wpT);

  k_embed<<<(N_NODESC + 63) / 64, 256, 0, stream>>>(x, emb, waB, hf, s1s, s1d);
  k_agg1<<<N_NODESC / 4, 256, 0, stream>>>(rowstart, esrc, hf, s1s, s1d, agg8);
  k_fused12<<<N_NODESC / 16, 256, 0, stream>>>(agg8, w1bT, b1, w2bT, w2sv, w2dv,
                                               hp2h, s2s, s2d);
  k_agg2<<<N_NODESC / 4, 256, 0, stream>>>(rowstart, esrc, hp2h, s2s, s2d, b2, batch, pooled);

  k_final<<<dim3(VOCAB_C / 320, N_GR / 16), 256, 0, stream>>>(pooled, wpT, bp, out);
}

// Round 21
// 218.978 us; speedup vs baseline: 1.2130x; 1.0713x over previous
//
#include <hip/hip_runtime.h>
#include <hip/hip_bf16.h>
#include <hip/hip_fp16.h>

#define N_NODESC 50000
#define N_EDGESC 500000
#define E_TOT    (N_EDGESC + N_NODESC)   // 550000, with self loops
#define HID      64
#define HEADS_C  8
#define F1       (HEADS_C * HID)         // 512
#define VOCAB_C  40000
#define N_GR     512
#define SCAN_B   196                     // ceil(50000/256)

typedef __attribute__((ext_vector_type(8))) short bf16x8;
typedef __attribute__((ext_vector_type(4))) float f32x4;
typedef __attribute__((ext_vector_type(8))) _Float16 half8;

__device__ __forceinline__ float lrelu(float x) { return x > 0.f ? x : 0.2f * x; }
__device__ __forceinline__ float bf2f(unsigned short u) {
  return __uint_as_float(((unsigned int)u) << 16);
}
__device__ __forceinline__ unsigned short f2bf(float f) {
  unsigned int u = __float_as_uint(f);
  unsigned int r = (u + 0x7fffu + ((u >> 16) & 1u)) >> 16;
  return (unsigned short)r;
}
__device__ __forceinline__ unsigned short f2h(float f) {
  __half h = __float2half(f);
  union { __half h; unsigned short u; } c; c.h = h; return c.u;
}
__device__ __forceinline__ __half2 as_h2(unsigned int v) {
  union { unsigned int u; __half2 h; } c; c.u = v; return c.h;
}
__device__ __forceinline__ unsigned int h2u(__half2 h) {
  union { __half2 h; unsigned int u; } c; c.h = h; return c.u;
}

// ---- zero scratch -------------------------------------------------------
__global__ void k_zero(int* __restrict__ deg, float* __restrict__ pooled) {
  int i = blockIdx.x * 256 + threadIdx.x;
  if (i < N_NODESC) deg[i] = 0;
  if (i < N_GR * HID) pooled[i] = 0.f;
}

// ---- CSR build: deg + per-edge slot in one pass -------------------------
__global__ void k_deg(const int* __restrict__ ei, int* __restrict__ deg,
                      int* __restrict__ eslot) {
  int e = blockIdx.x * blockDim.x + threadIdx.x;
  if (e >= E_TOT) return;
  int dst = (e < N_EDGESC) ? ei[N_EDGESC + e] : (e - N_EDGESC);
  eslot[e] = atomicAdd(&deg[dst], 1);
}

__global__ __launch_bounds__(256) void k_scan1(const int* __restrict__ deg,
                                               int* __restrict__ rowtmp,
                                               int* __restrict__ partials) {
  __shared__ int sh[256];
  int b = blockIdx.x, t = threadIdx.x, i = b * 256 + t;
  int d = (i < N_NODESC) ? deg[i] : 0;
  sh[t] = d;
  __syncthreads();
  for (int o = 1; o < 256; o <<= 1) {
    int v = (t >= o) ? sh[t - o] : 0;
    __syncthreads();
    sh[t] += v;
    __syncthreads();
  }
  if (i < N_NODESC) rowtmp[i] = sh[t];  // inclusive within block
  if (t == 255) partials[b] = sh[255];  // raw block total
}

__global__ __launch_bounds__(256) void k_scan3(const int* __restrict__ deg,
                                               const int* __restrict__ rowtmp,
                                               const int* __restrict__ partials,
                                               int* __restrict__ rowstart) {
  __shared__ int wsum[4];
  int b = blockIdx.x, t = threadIdx.x;
  int acc = 0;
  for (int i = t; i < b; i += 256) acc += partials[i];
#pragma unroll
  for (int o = 32; o; o >>= 1) acc += __shfl_xor(acc, o);
  if ((t & 63) == 0) wsum[t >> 6] = acc;
  __syncthreads();
  int base = wsum[0] + wsum[1] + wsum[2] + wsum[3];
  int i = b * 256 + t;
  if (i < N_NODESC) rowstart[i] = base + rowtmp[i] - deg[i];  // exclusive
  if (i == N_NODESC - 1) rowstart[N_NODESC] = base + rowtmp[i];
}

__global__ void k_scatter(const int* __restrict__ ei, const int* __restrict__ rowstart,
                          const int* __restrict__ eslot, int* __restrict__ esrc) {
  int e = blockIdx.x * blockDim.x + threadIdx.x;
  if (e >= E_TOT) return;
  int src, dst;
  if (e < N_EDGESC) { src = ei[e]; dst = ei[N_EDGESC + e]; }
  else { src = dst = e - N_EDGESC; }
  esrc[rowstart[dst] + eslot[e]] = src;
}

// ---- prep folds + weight converts + Wp transpose, one kernel ------------
__global__ __launch_bounds__(512) void k_prepwconv(const float* __restrict__ W1,
                                                   const float* __restrict__ as1,
                                                   const float* __restrict__ ad1,
                                                   const float* __restrict__ W2,
                                                   const float* __restrict__ as2,
                                                   const float* __restrict__ ad2,
                                                   const float* __restrict__ Wp,
                                                   float* __restrict__ w2sv,
                                                   float* __restrict__ w2dv,
                                                   unsigned short* __restrict__ waB,
                                                   unsigned short* __restrict__ w1bT,
                                                   unsigned short* __restrict__ w2bT,
                                                   unsigned short* __restrict__ wpT) {
  __shared__ float ws[64][65];
  int b = blockIdx.x, t = threadIdx.x;
  if (b < 64) {
    int g = b * 512 + t;
    int c = g >> 6, k = g & 63;
    w1bT[g] = f2bf(W1[(size_t)k * F1 + c]);
  } else if (b < 128) {
    int idx = (b - 64) * 512 + t;
    int c = idx >> 9, k = idx & 511;
    w2bT[idx] = f2bf(W2[(size_t)k * HID + c]);
  } else if (b == 128) {
    int k = t >> 3, h = t & 7;
    float ss = 0.f, dd = 0.f;
    for (int c = 0; c < 64; ++c) {
      float w = W1[k * F1 + h * 64 + c];
      ss += w * as1[h * 64 + c];
      dd += w * ad1[h * 64 + c];
    }
    waB[h * 64 + k] = f2bf(ss);
    waB[(8 + h) * 64 + k] = f2bf(dd);
    float s2 = 0.f, d2 = 0.f;
    for (int c = 0; c < 64; ++c) {
      float w = W2[t * 64 + c];
      s2 += w * as2[c];
      d2 += w * ad2[c];
    }
    w2sv[t] = s2;
    w2dv[t] = d2;
  } else {
    int v0 = (b - 129) * 64;
#pragma unroll
    for (int rep = 0; rep < 8; ++rep) {
      int idx = rep * 512 + t;
      int k = idx >> 6, v = idx & 63;
      ws[k][v] = Wp[(size_t)k * VOCAB_C + v0 + v];
    }
    __syncthreads();
#pragma unroll
    for (int rep = 0; rep < 8; ++rep) {
      int idx = rep * 512 + t;
      int v = idx >> 6, k = idx & 63;
      wpT[(size_t)(v0 + v) * 64 + k] = f2bf(ws[k][v]);
    }
  }
}

// ---- embed gather -> f16 rows + scores1 via bf16 MFMA -------------------
__global__ __launch_bounds__(256) void k_embed(const int* __restrict__ x,
                                               const float* __restrict__ emb,
                                               const unsigned short* __restrict__ waB,
                                               unsigned short* __restrict__ hf,
                                               float* __restrict__ s1s,
                                               float* __restrict__ s1d) {
  int t = threadIdx.x;
  int w = t >> 6, lane = t & 63;
  int lrow = lane & 15, lq = lane >> 4;
  int n0 = blockIdx.x * 64 + w * 16;
  if (n0 >= N_NODESC) return;
  int node = n0 + lrow;
  const float* er = emb + (size_t)x[node] * 64;
  float4 f0 = *reinterpret_cast<const float4*>(er + lq * 8);
  float4 f1 = *reinterpret_cast<const float4*>(er + lq * 8 + 4);
  float4 f2 = *reinterpret_cast<const float4*>(er + 32 + lq * 8);
  float4 f3 = *reinterpret_cast<const float4*>(er + 32 + lq * 8 + 4);
  bf16x8 a0, a1;
  a0[0] = (short)f2bf(f0.x); a0[1] = (short)f2bf(f0.y);
  a0[2] = (short)f2bf(f0.z); a0[3] = (short)f2bf(f0.w);
  a0[4] = (short)f2bf(f1.x); a0[5] = (short)f2bf(f1.y);
  a0[6] = (short)f2bf(f1.z); a0[7] = (short)f2bf(f1.w);
  a1[0] = (short)f2bf(f2.x); a1[1] = (short)f2bf(f2.y);
  a1[2] = (short)f2bf(f2.z); a1[3] = (short)f2bf(f2.w);
  a1[4] = (short)f2bf(f3.x); a1[5] = (short)f2bf(f3.y);
  a1[6] = (short)f2bf(f3.z); a1[7] = (short)f2bf(f3.w);
  half8 h0, h1;
  h0[0] = (_Float16)f0.x; h0[1] = (_Float16)f0.y;
  h0[2] = (_Float16)f0.z; h0[3] = (_Float16)f0.w;
  h0[4] = (_Float16)f1.x; h0[5] = (_Float16)f1.y;
  h0[6] = (_Float16)f1.z; h0[7] = (_Float16)f1.w;
  h1[0] = (_Float16)f2.x; h1[1] = (_Float16)f2.y;
  h1[2] = (_Float16)f2.z; h1[3] = (_Float16)f2.w;
  h1[4] = (_Float16)f3.x; h1[5] = (_Float16)f3.y;
  h1[6] = (_Float16)f3.z; h1[7] = (_Float16)f3.w;
  *reinterpret_cast<half8*>(&hf[(size_t)node * 64 + lq * 8]) = h0;
  *reinterpret_cast<half8*>(&hf[(size_t)node * 64 + 32 + lq * 8]) = h1;
  const bf16x8* brow = reinterpret_cast<const bf16x8*>(waB + lrow * 64 + lq * 8);
  f32x4 acc = {};
  acc = __builtin_amdgcn_mfma_f32_16x16x32_bf16(a0, brow[0], acc, 0, 0, 0);
  acc = __builtin_amdgcn_mfma_f32_16x16x32_bf16(a1, brow[4], acc, 0, 0, 0);
  float* dst = (lrow < 8) ? s1s : s1d;
  int h = lrow & 7;
#pragma unroll
  for (int r = 0; r < 4; ++r)
    dst[(size_t)(n0 + lq * 4 + r) * 8 + h] = acc[r];
}

// ---- layer-1 aggregate: batched gather (8 loads in flight) --------------
__global__ __launch_bounds__(256) void k_agg1(const int* __restrict__ rowstart,
                                              const int* __restrict__ esrc,
                                              const unsigned short* __restrict__ hf,
                                              const float* __restrict__ s1s,
                                              const float* __restrict__ s1d,
                                              unsigned short* __restrict__ agg8) {
  int n = blockIdx.x * 4 + (threadIdx.x >> 6);
  int L = threadIdx.x & 63;
  int eh = L >> 3;  // edge slot (p-phase)
  int hh = L & 7;   // head (p-phase)
  int myh = L >> 3; // head of this lane's output slice
  const int fc = (L & 7) * 8;  // feature chunk in 64-dim embedding
  int r0 = rowstart[n], dg = rowstart[n + 1] - r0;
  float sdst = s1d[n * 8 + hh];
  __half2 ac0 = __float2half2_rn(0.f), ac1 = ac0, ac2 = ac0, ac3 = ac0;
  float dsum = 0.f;
  for (int base = 0; base < dg; base += 8) {
    int i = base + eh;
    float p = 0.f;
    int s = 0;
    if (i < dg) {
      s = esrc[r0 + i];
      p = __expf(lrelu(s1s[s * 8 + hh] + sdst));
    }
    dsum += p;
    int cnt = min(8, dg - base);
    if (cnt == 8) {
      int sjs[8];
#pragma unroll
      for (int j = 0; j < 8; ++j) sjs[j] = __shfl(s, j << 3);
      uint4 us[8];
#pragma unroll
      for (int j = 0; j < 8; ++j)
        us[j] = *reinterpret_cast<const uint4*>(&hf[(size_t)sjs[j] * 64 + fc]);
#pragma unroll
      for (int j = 0; j < 8; ++j) {
        __half2 p2 = __float2half2_rn(__shfl(p, (j << 3) | myh));
        ac0 = __hfma2(as_h2(us[j].x), p2, ac0);
        ac1 = __hfma2(as_h2(us[j].y), p2, ac1);
        ac2 = __hfma2(as_h2(us[j].z), p2, ac2);
        ac3 = __hfma2(as_h2(us[j].w), p2, ac3);
      }
    } else {
      for (int j = 0; j < cnt; ++j) {
        float pj = __shfl(p, (j << 3) | myh);
        int sj = __shfl(s, j << 3);
        uint4 u = *reinterpret_cast<const uint4*>(&hf[(size_t)sj * 64 + fc]);
        __half2 p2 = __float2half2_rn(pj);
        ac0 = __hfma2(as_h2(u.x), p2, ac0);
        ac1 = __hfma2(as_h2(u.y), p2, ac1);
        ac2 = __hfma2(as_h2(u.z), p2, ac2);
        ac3 = __hfma2(as_h2(u.w), p2, ac3);
      }
    }
  }
  dsum += __shfl_xor(dsum, 8);
  dsum += __shfl_xor(dsum, 16);
  dsum += __shfl_xor(dsum, 32);
  float inv = 1.f / (__shfl(dsum, myh) + 1e-16f);
  float2 v0 = __half22float2(ac0);
  float2 v1 = __half22float2(ac1);
  float2 v2 = __half22float2(ac2);
  float2 v3 = __half22float2(ac3);
  uint4 ov;
  ov.x = (unsigned int)f2bf(v0.x * inv) | ((unsigned int)f2bf(v0.y * inv) << 16);
  ov.y = (unsigned int)f2bf(v1.x * inv) | ((unsigned int)f2bf(v1.y * inv) << 16);
  ov.z = (unsigned int)f2bf(v2.x * inv) | ((unsigned int)f2bf(v2.y * inv) << 16);
  ov.w = (unsigned int)f2bf(v3.x * inv) | ((unsigned int)f2bf(v3.y * inv) << 16);
  *reinterpret_cast<uint4*>(&agg8[(size_t)n * F1 + L * 8]) = ov;
}

// ---- fused: 32 nodes/block, two 16-row tiles sharing all B loads --------
__global__ __launch_bounds__(256) void k_fused12(const unsigned short* __restrict__ agg8,
                                                 const unsigned short* __restrict__ w1bT,
                                                 const float* __restrict__ b1,
                                                 const unsigned short* __restrict__ w2bT,
                                                 const float* __restrict__ w2sv,
                                                 const float* __restrict__ w2dv,
                                                 unsigned short* __restrict__ hp2h,
                                                 float* __restrict__ s2s,
                                                 float* __restrict__ s2d) {
  __shared__ unsigned short Ts[32][520];   // 33.3 KB
  __shared__ float bs[512], wsv[512], wdv[512];
  __shared__ float sredS[4][32], sredD[4][32];
  int t = threadIdx.x;
  int n0 = blockIdx.x * 32;
  bool hasT1 = (n0 + 16) < N_NODESC;
  int n1 = hasT1 ? (n0 + 16) : n0;
  bs[t] = b1[t]; bs[t + 256] = b1[t + 256];
  wsv[t] = w2sv[t]; wsv[t + 256] = w2sv[t + 256];
  wdv[t] = w2dv[t]; wdv[t + 256] = w2dv[t + 256];
  int w = t >> 6, lane = t & 63;
  int lrow = lane & 15, lq = lane >> 4;
  // ---- stage 1: both tiles' A-frags; B loaded once, used 4x
  const unsigned short* arow0 = agg8 + (size_t)(n0 + lrow) * F1;
  const unsigned short* arow1 = agg8 + (size_t)(n1 + lrow) * F1;
  int h0 = 2 * w;
  bf16x8 a00 = *reinterpret_cast<const bf16x8*>(arow0 + h0 * 64 + lq * 8);
  bf16x8 a01 = *reinterpret_cast<const bf16x8*>(arow0 + h0 * 64 + 32 + lq * 8);
  bf16x8 a10 = *reinterpret_cast<const bf16x8*>(arow0 + (h0 + 1) * 64 + lq * 8);
  bf16x8 a11 = *reinterpret_cast<const bf16x8*>(arow0 + (h0 + 1) * 64 + 32 + lq * 8);
  bf16x8 c00 = *reinterpret_cast<const bf16x8*>(arow1 + h0 * 64 + lq * 8);
  bf16x8 c01 = *reinterpret_cast<const bf16x8*>(arow1 + h0 * 64 + 32 + lq * 8);
  bf16x8 c10 = *reinterpret_cast<const bf16x8*>(arow1 + (h0 + 1) * 64 + lq * 8);
  bf16x8 c11 = *reinterpret_cast<const bf16x8*>(arow1 + (h0 + 1) * 64 + 32 + lq * 8);
  int c0 = w * 128;
  f32x4 acc0[8] = {}, acc1[8] = {};
#pragma unroll
  for (int ct = 0; ct < 8; ++ct) {
    int col = c0 + ct * 16 + lrow;
    const bf16x8* brow = reinterpret_cast<const bf16x8*>(w1bT + (size_t)col * 64 + lq * 8);
    bf16x8 b0 = brow[0], b4 = brow[4];
    if (ct < 4) {
      acc0[ct] = __builtin_amdgcn_mfma_f32_16x16x32_bf16(a00, b0, acc0[ct], 0, 0, 0);
      acc0[ct] = __builtin_amdgcn_mfma_f32_16x16x32_bf16(a01, b4, acc0[ct], 0, 0, 0);
      acc1[ct] = __builtin_amdgcn_mfma_f32_16x16x32_bf16(c00, b0, acc1[ct], 0, 0, 0);
      acc1[ct] = __builtin_amdgcn_mfma_f32_16x16x32_bf16(c01, b4, acc1[ct], 0, 0, 0);
    } else {
      acc0[ct] = __builtin_amdgcn_mfma_f32_16x16x32_bf16(a10, b0, acc0[ct], 0, 0, 0);
      acc0[ct] = __builtin_amdgcn_mfma_f32_16x16x32_bf16(a11, b4, acc0[ct], 0, 0, 0);
      acc1[ct] = __builtin_amdgcn_mfma_f32_16x16x32_bf16(c10, b0, acc1[ct], 0, 0, 0);
      acc1[ct] = __builtin_amdgcn_mfma_f32_16x16x32_bf16(c11, b4, acc1[ct], 0, 0, 0);
    }
  }
  __syncthreads();  // bs/wsv/wdv ready; Ts free
  // ---- epilogue: bias+ELU -> Ts; scores2 partials (both tiles)
  float ssp0[4] = {}, ddp0[4] = {}, ssp1[4] = {}, ddp1[4] = {};
#pragma unroll
  for (int ct = 0; ct < 8; ++ct) {
    int col = c0 + ct * 16 + lrow;
#pragma unroll
    for (int r = 0; r < 4; ++r) {
      float v = acc0[ct][r] + bs[col];
      v = v > 0.f ? v : (__expf(v) - 1.f);
      Ts[lq * 4 + r][col] = f2bf(v);
      ssp0[r] += v * wsv[col];
      ddp0[r] += v * wdv[col];
      float u = acc1[ct][r] + bs[col];
      u = u > 0.f ? u : (__expf(u) - 1.f);
      Ts[16 + lq * 4 + r][col] = f2bf(u);
      ssp1[r] += u * wsv[col];
      ddp1[r] += u * wdv[col];
    }
  }
#pragma unroll
  for (int r = 0; r < 4; ++r) {
#pragma unroll
    for (int o = 1; o < 16; o <<= 1) {
      ssp0[r] += __shfl_xor(ssp0[r], o);
      ddp0[r] += __shfl_xor(ddp0[r], o);
      ssp1[r] += __shfl_xor(ssp1[r], o);
      ddp1[r] += __shfl_xor(ddp1[r], o);
    }
  }
  if (lrow == 0) {
#pragma unroll
    for (int r = 0; r < 4; ++r) {
      sredS[w][lq * 4 + r] = ssp0[r];
      sredD[w][lq * 4 + r] = ddp0[r];
      sredS[w][16 + lq * 4 + r] = ssp1[r];
      sredD[w][16 + lq * 4 + r] = ddp1[r];
    }
  }
  __syncthreads();  // Ts complete + sred ready
  // ---- stage 2: hp2 = h1 @ W2 (wave w: cols [16w,16w+16)); B used 2x
  f32x4 acc2_0 = {}, acc2_1 = {};
  const unsigned short* bcolp = w2bT + (size_t)(w * 16 + lrow) * F1;
#pragma unroll 4
  for (int kq = 0; kq < 16; ++kq) {
    int kbase = kq * 32 + lq * 8;
    bf16x8 b = *reinterpret_cast<const bf16x8*>(bcolp + kbase);
    bf16x8 aT0 = *reinterpret_cast<const bf16x8*>(&Ts[lrow][kbase]);
    bf16x8 aT1 = *reinterpret_cast<const bf16x8*>(&Ts[16 + lrow][kbase]);
    acc2_0 = __builtin_amdgcn_mfma_f32_16x16x32_bf16(aT0, b, acc2_0, 0, 0, 0);
    acc2_1 = __builtin_amdgcn_mfma_f32_16x16x32_bf16(aT1, b, acc2_1, 0, 0, 0);
  }
  if (t < 32 && (n0 + t) < N_NODESC) {
    s2s[n0 + t] = sredS[0][t] + sredS[1][t] + sredS[2][t] + sredS[3][t];
    s2d[n0 + t] = sredD[0][t] + sredD[1][t] + sredD[2][t] + sredD[3][t];
  }
#pragma unroll
  for (int r = 0; r < 4; ++r) {
    hp2h[(size_t)(n0 + lq * 4 + r) * HID + w * 16 + lrow] = f2h(acc2_0[r]);
    if (hasT1)
      hp2h[(size_t)(n0 + 16 + lq * 4 + r) * HID + w * 16 + lrow] = f2h(acc2_1[r]);
  }
}

// ---- layer-2 aggregate: batched gather (16 loads in flight) -------------
__global__ __launch_bounds__(256) void k_agg2(const int* __restrict__ rowstart,
                                              const int* __restrict__ esrc,
                                              const unsigned short* __restrict__ hp2h,
                                              const float* __restrict__ s2s,
                                              const float* __restrict__ s2d,
                                              const float* __restrict__ b2,
                                              const int* __restrict__ batch,
                                              float* __restrict__ pooled) {
  int n = blockIdx.x * 4 + (threadIdx.x >> 6);
  int lane = threadIdx.x & 63;
  int half = lane >> 5;
  int fl = lane & 31;
  int r0 = rowstart[n], dg = rowstart[n + 1] - r0;
  float sdst = s2d[n];
  __half2 ac = __float2half2_rn(0.f);
  float dsum = 0.f;
  for (int base = 0; base < dg; base += 32) {
    int i = base + fl;
    float p = 0.f;
    int s = 0;
    if (i < dg) {
      s = esrc[r0 + i];
      p = __expf(lrelu(s2s[s] + sdst));
    }
    dsum += p;
    int cnt = min(32, dg - base);
    if (cnt == 32) {
      int sjs[16];
#pragma unroll
      for (int jj = 0; jj < 16; ++jj) sjs[jj] = __shfl(s, 2 * jj + half, 32);
      unsigned int us[16];
#pragma unroll
      for (int jj = 0; jj < 16; ++jj)
        us[jj] = *reinterpret_cast<const unsigned int*>(&hp2h[(size_t)sjs[jj] * 64 + fl * 2]);
#pragma unroll
      for (int jj = 0; jj < 16; ++jj) {
        float pj = __shfl(p, 2 * jj + half, 32);
        ac = __hfma2(as_h2(us[jj]), __float2half2_rn(pj), ac);
      }
    } else {
      for (int j = 0; j < cnt; j += 2) {
        int jj = j + half;
        float pj = __shfl(p, jj, 32);
        int sj = __shfl(s, jj, 32);
        unsigned int hv = *reinterpret_cast<const unsigned int*>(&hp2h[(size_t)sj * 64 + fl * 2]);
        ac = __hfma2(as_h2(hv), __float2half2_rn(pj), ac);
      }
    }
  }
#pragma unroll
  for (int o = 1; o < 32; o <<= 1) dsum += __shfl_xor(dsum, o);
  float inv = 1.f / (dsum + 1e-16f);
  unsigned int other = __shfl_xor(h2u(ac), 32);
  ac = __hadd2(ac, as_h2(other));
  float2 fv = __half22float2(ac);
  int f = 2 * fl + half;
  float o = (half ? fv.y : fv.x) * inv + b2[f];
  atomicAdd(&pooled[batch[n] * 64 + f], o);
}

// ---- final via MFMA: out[512,40000] = pooled @ Wp + bp ------------------
__global__ __launch_bounds__(256) void k_final(const float* __restrict__ pooled,
                                               const unsigned short* __restrict__ wpT,
                                               const float* __restrict__ bp,
                                               float* __restrict__ out) {
  __shared__ unsigned short As[16][72];
  __shared__ float Cs[16][324];
  int t = threadIdx.x;
  int g0 = blockIdx.y * 16;
  int vb = blockIdx.x * 320;
  {
    int g = t >> 4, k4 = (t & 15) * 4;
    float4 pv = *reinterpret_cast<const float4*>(&pooled[(size_t)(g0 + g) * 64 + k4]);
    ushort4 u;
    u.x = f2bf(pv.x); u.y = f2bf(pv.y); u.z = f2bf(pv.z); u.w = f2bf(pv.w);
    *reinterpret_cast<ushort4*>(&As[g][k4]) = u;
  }
  __syncthreads();
  int w = t >> 6, lane = t & 63;
  int lrow = lane & 15, lq = lane >> 4;
  bf16x8 a0 = *reinterpret_cast<const bf16x8*>(&As[lrow][lq * 8]);
  bf16x8 a1 = *reinterpret_cast<const bf16x8*>(&As[lrow][32 + lq * 8]);
#pragma unroll
  for (int ct = 0; ct < 5; ++ct) {
    int cloc = (w * 5 + ct) * 16 + lrow;
    const bf16x8* brow = reinterpret_cast<const bf16x8*>(wpT + (size_t)(vb + cloc) * 64 + lq * 8);
    f32x4 acc = {};
    acc = __builtin_amdgcn_mfma_f32_16x16x32_bf16(a0, brow[0], acc, 0, 0, 0);
    acc = __builtin_amdgcn_mfma_f32_16x16x32_bf16(a1, brow[4], acc, 0, 0, 0);
#pragma unroll
    for (int r = 0; r < 4; ++r) Cs[lq * 4 + r][cloc] = acc[r];
  }
  __syncthreads();
  for (int i = t; i < 1280; i += 256) {
    int r = i / 80, c = i % 80;
    float4 cv = *reinterpret_cast<const float4*>(&Cs[r][c * 4]);
    float4 bv = *reinterpret_cast<const float4*>(&bp[vb + c * 4]);
    cv.x += bv.x; cv.y += bv.y; cv.z += bv.z; cv.w += bv.w;
    *reinterpret_cast<float4*>(&out[(size_t)(g0 + r) * VOCAB_C + vb + c * 4]) = cv;
  }
}

extern "C" void kernel_launch(void* const* d_in, const int* in_sizes, int n_in,
                              void* d_out, int out_size, void* d_ws, size_t ws_size,
                              hipStream_t stream) {
  const int*   x     = (const int*)d_in[0];
  const int*   ei    = (const int*)d_in[1];
  const int*   batch = (const int*)d_in[2];
  const float* emb   = (const float*)d_in[3];
  const float* W1    = (const float*)d_in[4];
  const float* as1   = (const float*)d_in[5];
  const float* ad1   = (const float*)d_in[6];
  const float* b1    = (const float*)d_in[7];
  const float* W2    = (const float*)d_in[8];
  const float* as2   = (const float*)d_in[9];
  const float* ad2   = (const float*)d_in[10];
  const float* b2    = (const float*)d_in[11];
  const float* Wp    = (const float*)d_in[12];
  const float* bp    = (const float*)d_in[13];
  float* out = (float*)d_out;

  char* ws = (char*)d_ws;
  size_t off = 0;
#define WS_ALLOC(T, name, bytes) T name = (T)(ws + off); off += (((size_t)(bytes)) + 255) & ~(size_t)255;
  WS_ALLOC(unsigned short*, hf,   (size_t)N_NODESC * HID * 2)
  WS_ALLOC(unsigned short*, agg8, (size_t)N_NODESC * F1 * 2)
  WS_ALLOC(unsigned short*, hp2h, (size_t)N_NODESC * HID * 2)
  WS_ALLOC(unsigned short*, w1bT, 512 * 64 * 2)
  WS_ALLOC(unsigned short*, w2bT, 64 * 512 * 2)
  WS_ALLOC(unsigned short*, wpT,  (size_t)VOCAB_C * HID * 2)
  WS_ALLOC(unsigned short*, waB,  16 * 64 * 2)
  WS_ALLOC(float*, s1s,  (size_t)N_NODESC * HEADS_C * 4)
  WS_ALLOC(float*, s1d,  (size_t)N_NODESC * HEADS_C * 4)
  WS_ALLOC(float*, s2s,  (size_t)N_NODESC * 4)
  WS_ALLOC(float*, s2d,  (size_t)N_NODESC * 4)
  WS_ALLOC(float*, pooled, (size_t)N_GR * HID * 4)
  WS_ALLOC(float*, w2sv, 512 * 4)
  WS_ALLOC(float*, w2dv, 512 * 4)
  WS_ALLOC(int*,   deg,      (size_t)N_NODESC * 4)
  WS_ALLOC(int*,   rowstart, (size_t)(N_NODESC + 1) * 4)
  WS_ALLOC(int*,   rowtmp,   (size_t)N_NODESC * 4)
  WS_ALLOC(int*,   partials, 256 * 4)
  WS_ALLOC(int*,   eslot,    (size_t)E_TOT * 4)
  WS_ALLOC(int*,   esrc,     (size_t)E_TOT * 4)
#undef WS_ALLOC
  (void)ws_size; (void)in_sizes; (void)n_in; (void)out_size;

  int ethreads = 256, eblocks = (E_TOT + 255) / 256;
  k_zero<<<SCAN_B, 256, 0, stream>>>(deg, pooled);
  k_deg<<<eblocks, ethreads, 0, stream>>>(ei, deg, eslot);
  k_scan1<<<SCAN_B, 256, 0, stream>>>(deg, rowtmp, partials);
  k_scan3<<<SCAN_B, 256, 0, stream>>>(deg, rowtmp, partials, rowstart);
  k_scatter<<<eblocks, ethreads, 0, stream>>>(ei, rowstart, eslot, esrc);
  k_prepwconv<<<129 + VOCAB_C / 64, 512, 0, stream>>>(
      W1, as1, ad1, W2, as2, ad2, Wp,
      w2sv, w2dv, waB, w1bT, w2bT, wpT);

  k_embed<<<(N_NODESC + 63) / 64, 256, 0, stream>>>(x, emb, waB, hf, s1s, s1d);
  k_agg1<<<N_NODESC / 4, 256, 0, stream>>>(rowstart, esrc, hf, s1s, s1d, agg8);
  k_fused12<<<(N_NODESC + 31) / 32, 256, 0, stream>>>(agg8, w1bT, b1, w2bT, w2sv, w2dv,
                                                      hp2h, s2s, s2d);
  k_agg2<<<N_NODESC / 4, 256, 0, stream>>>(rowstart, esrc, hp2h, s2s, s2d, b2, batch, pooled);

  k_final<<<dim3(VOCAB_C / 320, N_GR / 16), 256, 0, stream>>>(pooled, wpT, bp, out);
}